// Round 4
// baseline (74.090 us; speedup 1.0000x reference)
//
#include <hip/hip_runtime.h>
#include <math.h>

#define BB 64
#define SS 32
#define DD 1024
#define HH 1024

__device__ __forceinline__ float gelu_exact(float x) {
    return 0.5f * x * (1.0f + erff(x * 0.7071067811865476f));
}

// ws layout:
//   [0, 256)        idx int[64]
//   [256, 8448)     logits float[64][32]
//   [32768, ...)    part  float[2][64][DSPL][1024]
#define WS_LOGITS 256
#define WS_PART   32768

// ---------------- Kernel A1: one logit per block ----------------
__global__ __launch_bounds__(256) void logits_kernel(
    const float* __restrict__ descs_t, const float* __restrict__ descs_rot,
    const float* __restrict__ scene_w, float* __restrict__ logits)
{
    const int s = blockIdx.x, b = blockIdx.y;
    const int tid = threadIdx.x, lane = tid & 63, wave = tid >> 6;

    const float4* t4 = (const float4*)(descs_t  + ((size_t)b * SS + s) * DD);
    const float4* r4 = (const float4*)(descs_rot + ((size_t)b * SS + s) * DD);
    const float4* w4t = (const float4*)(scene_w);
    const float4* w4r = (const float4*)(scene_w + DD);

    float4 a = t4[tid], w = w4t[tid];
    float acc = a.x*w.x + a.y*w.y + a.z*w.z + a.w*w.w;
    float4 a2 = r4[tid], w2 = w4r[tid];
    acc += a2.x*w2.x + a2.y*w2.y + a2.z*w2.z + a2.w*w2.w;

    #pragma unroll
    for (int off = 32; off >= 1; off >>= 1) acc += __shfl_xor(acc, off, 64);

    __shared__ float red[4];
    if (lane == 0) red[wave] = acc;
    __syncthreads();
    if (tid == 0) logits[b * SS + s] = red[0] + red[1] + red[2] + red[3];
}

// ---------------- Kernel A2: softmax/argmax (1 wave) ----------------
__global__ __launch_bounds__(64) void finalize_scene_kernel(
    const float* __restrict__ scene_b, float* __restrict__ logits,
    int* __restrict__ idx_ws, float* __restrict__ out)
{
    const int b = threadIdx.x;
    const float bias = scene_b[0];
    float lg[SS];
    float m = -1e30f; int am = 0;
    #pragma unroll
    for (int s = 0; s < SS; ++s) {
        lg[s] = logits[b * SS + s] + bias;
        if (lg[s] > m) { m = lg[s]; am = s; }   // first-max tie-break
    }
    float sum = 0.f;
    #pragma unroll
    for (int s = 0; s < SS; ++s) sum += expf(lg[s] - m);
    const float lse = m + logf(sum);
    #pragma unroll
    for (int s = 0; s < SS; ++s) out[BB * 7 + b * SS + s] = lg[s] - lse;
    idx_ws[b] = am;
}

// ---------------- Kernel B: layer-1 matvec, PER SAMPLE ----------------
// grid (DSPL, BB, 2): block handles 1 sample's DS-row x 1024-col slice of W1[idx[b]].
// Per thread: 4 consecutive H-columns, one float4 accumulator, 16 loads in flight.
template<int DSPL>
__global__ __launch_bounds__(256) void layer1_kernel(
    const float* __restrict__ descs_t, const float* __restrict__ descs_rot,
    const float* __restrict__ Wt1, const float* __restrict__ Wr1,
    const int* __restrict__ idx_ws, float* __restrict__ part)
{
    constexpr int DS = DD / DSPL;      // rows per block
    const int dsp  = blockIdx.x;
    const int b    = blockIdx.y;
    const int head = blockIdx.z;
    const int tid  = threadIdx.x;
    const int s    = idx_ws[b];

    __shared__ float sh_g[DS];
    const float* descs = head ? descs_rot : descs_t;
    if (tid < DS / 4) {
        ((float4*)sh_g)[tid] =
            ((const float4*)(descs + ((size_t)b * SS + s) * DD + dsp * DS))[tid];
    }
    __syncthreads();

    const float* W = (head ? Wr1 : Wt1)
                   + (size_t)s * DD * HH + (size_t)dsp * DS * HH + tid * 4;
    float4 acc = make_float4(0.f, 0.f, 0.f, 0.f);

    #pragma unroll
    for (int d0 = 0; d0 < DS; d0 += 16) {
        float4 w[16];
        #pragma unroll
        for (int r = 0; r < 16; ++r)
            w[r] = *(const float4*)(W + (size_t)(d0 + r) * HH);
        #pragma unroll
        for (int r = 0; r < 16; ++r) {
            const float g = sh_g[d0 + r];
            acc.x += g * w[r].x; acc.y += g * w[r].y;
            acc.z += g * w[r].z; acc.w += g * w[r].w;
        }
    }

    float* dst = part + (((size_t)(head * BB + b) * DSPL + dsp) * HH) + tid * 4;
    *(float4*)dst = acc;
}

// ---------------- Kernel C: bias + GELU + layer-2 + pose output ----------------
template<int DSPL>
__global__ __launch_bounds__(256) void head_out_kernel(
    const float* __restrict__ bt1, const float* __restrict__ Wt2, const float* __restrict__ bt2,
    const float* __restrict__ br1, const float* __restrict__ Wr2, const float* __restrict__ br2,
    const int* __restrict__ idx_ws, const float* __restrict__ part,
    float* __restrict__ out)
{
    const int b   = blockIdx.x;
    const int tid = threadIdx.x;
    const int s   = idx_ws[b];

    __shared__ float sh_h[2][HH];
    __shared__ float sh_red[7][4];

    #pragma unroll
    for (int head = 0; head < 2; ++head) {
        const float* b1 = (head ? br1 : bt1) + (size_t)s * HH;
        const float* p0 = part + ((size_t)(head * BB + b) * DSPL) * HH;
        const int j = tid * 4;
        float4 a = *(const float4*)(p0 + j);
        #pragma unroll
        for (int dsp = 1; dsp < DSPL; ++dsp) {
            float4 q = *(const float4*)(p0 + (size_t)dsp * HH + j);
            a.x += q.x; a.y += q.y; a.z += q.z; a.w += q.w;
        }
        float4 bb = *(const float4*)(b1 + j);
        sh_h[head][j + 0] = gelu_exact(a.x + bb.x);
        sh_h[head][j + 1] = gelu_exact(a.y + bb.y);
        sh_h[head][j + 2] = gelu_exact(a.z + bb.z);
        sh_h[head][j + 3] = gelu_exact(a.w + bb.w);
    }
    __syncthreads();

    const float* wt2 = Wt2 + (size_t)s * HH * 3;
    const float* wr2 = Wr2 + (size_t)s * HH * 4;
    float pa[7] = {0.f, 0.f, 0.f, 0.f, 0.f, 0.f, 0.f};
    for (int j = tid; j < HH; j += 256) {
        float ht = sh_h[0][j];
        float hr = sh_h[1][j];
        pa[0] += ht * wt2[j * 3 + 0];
        pa[1] += ht * wt2[j * 3 + 1];
        pa[2] += ht * wt2[j * 3 + 2];
        pa[3] += hr * wr2[j * 4 + 0];
        pa[4] += hr * wr2[j * 4 + 1];
        pa[5] += hr * wr2[j * 4 + 2];
        pa[6] += hr * wr2[j * 4 + 3];
    }
    const int lane = tid & 63, wave = tid >> 6;
    #pragma unroll
    for (int o = 0; o < 7; ++o) {
        float v = pa[o];
        #pragma unroll
        for (int off = 32; off >= 1; off >>= 1) v += __shfl_xor(v, off, 64);
        if (lane == 0) sh_red[o][wave] = v;
    }
    __syncthreads();
    if (tid < 7) {
        float v = sh_red[tid][0] + sh_red[tid][1] + sh_red[tid][2] + sh_red[tid][3];
        float bias = (tid < 3) ? bt2[(size_t)s * 3 + tid] : br2[(size_t)s * 4 + (tid - 3)];
        out[b * 7 + tid] = v + bias;
    }
}

template<int DSPL>
static void launch_pipeline(const float* descs_t, const float* descs_rot,
                            const float* Wt1, const float* Wr1,
                            const float* bt1, const float* Wt2, const float* bt2,
                            const float* br1, const float* Wr2, const float* br2,
                            int* idx_ws, float* part,
                            float* out, hipStream_t stream) {
    layer1_kernel<DSPL><<<dim3(DSPL, BB, 2), dim3(256), 0, stream>>>(
        descs_t, descs_rot, Wt1, Wr1, idx_ws, part);
    head_out_kernel<DSPL><<<dim3(BB), dim3(256), 0, stream>>>(
        bt1, Wt2, bt2, br1, Wr2, br2, idx_ws, part, out);
}

extern "C" void kernel_launch(void* const* d_in, const int* in_sizes, int n_in,
                              void* d_out, int out_size, void* d_ws, size_t ws_size,
                              hipStream_t stream) {
    const float* descs_t   = (const float*)d_in[0];
    const float* descs_rot = (const float*)d_in[1];
    const float* scene_w   = (const float*)d_in[2];
    const float* scene_b   = (const float*)d_in[3];
    const float* Wt1 = (const float*)d_in[4];
    const float* bt1 = (const float*)d_in[5];
    const float* Wt2 = (const float*)d_in[6];
    const float* bt2 = (const float*)d_in[7];
    const float* Wr1 = (const float*)d_in[8];
    const float* br1 = (const float*)d_in[9];
    const float* Wr2 = (const float*)d_in[10];
    const float* br2 = (const float*)d_in[11];
    float* out = (float*)d_out;

    int*   idx_ws = (int*)d_ws;
    float* logits = (float*)((char*)d_ws + WS_LOGITS);
    float* part   = (float*)((char*)d_ws + WS_PART);

    logits_kernel<<<dim3(SS, BB), dim3(256), 0, stream>>>(
        descs_t, descs_rot, scene_w, logits);
    finalize_scene_kernel<<<dim3(1), dim3(64), 0, stream>>>(
        scene_b, logits, idx_ws, out);

    const size_t need16 = (size_t)WS_PART + (size_t)2 * BB * 16 * HH * sizeof(float);
    const size_t need8  = (size_t)WS_PART + (size_t)2 * BB * 8  * HH * sizeof(float);
    if (ws_size >= need16) {
        launch_pipeline<16>(descs_t, descs_rot, Wt1, Wr1, bt1, Wt2, bt2, br1, Wr2, br2,
                            idx_ws, part, out, stream);
    } else if (ws_size >= need8) {
        launch_pipeline<8>(descs_t, descs_rot, Wt1, Wr1, bt1, Wt2, bt2, br1, Wr2, br2,
                            idx_ws, part, out, stream);
    } else {
        launch_pipeline<4>(descs_t, descs_rot, Wt1, Wr1, bt1, Wt2, bt2, br1, Wr2, br2,
                            idx_ws, part, out, stream);
    }
}

// Round 5
// 56.651 us; speedup vs baseline: 1.3078x; 1.3078x over previous
//
#include <hip/hip_runtime.h>
#include <math.h>

#define BB 64
#define SS 32
#define DD 1024
#define HH 1024
#define NG 40          // group slots (worst case Sum ceil(c_s/8) = 36)
#define GG 8           // samples per group

__device__ __forceinline__ float gelu_exact(float x) {
    return 0.5f * x * (1.0f + erff(x * 0.7071067811865476f));
}

// ws layout:
//   [0, 256)        idx int[64]
//   [256, 8448)     logits float[64][32]
//   [8448, 8608)    grp_scene int[NG]
//   [8704, 9984)    grp_samp  int[NG][GG]
//   [32768, ...)    part float[2][64][DSPL][1024]
#define WS_LOGITS 256
#define WS_GSCENE 8448
#define WS_GSAMP  8704
#define WS_PART   32768

// ---------------- Kernel A1: one logit per block ----------------
__global__ __launch_bounds__(256) void logits_kernel(
    const float* __restrict__ descs_t, const float* __restrict__ descs_rot,
    const float* __restrict__ scene_w, float* __restrict__ logits)
{
    const int s = blockIdx.x, b = blockIdx.y;
    const int tid = threadIdx.x, lane = tid & 63, wave = tid >> 6;

    const float4* t4 = (const float4*)(descs_t  + ((size_t)b * SS + s) * DD);
    const float4* r4 = (const float4*)(descs_rot + ((size_t)b * SS + s) * DD);
    const float4* w4t = (const float4*)(scene_w);
    const float4* w4r = (const float4*)(scene_w + DD);

    float4 a = t4[tid], w = w4t[tid];
    float acc = a.x*w.x + a.y*w.y + a.z*w.z + a.w*w.w;
    float4 a2 = r4[tid], w2 = w4r[tid];
    acc += a2.x*w2.x + a2.y*w2.y + a2.z*w2.z + a2.w*w2.w;

    #pragma unroll
    for (int off = 32; off >= 1; off >>= 1) acc += __shfl_xor(acc, off, 64);

    __shared__ float red[4];
    if (lane == 0) red[wave] = acc;
    __syncthreads();
    if (tid == 0) logits[b * SS + s] = red[0] + red[1] + red[2] + red[3];
}

// ---------------- Kernel A2: softmax/argmax + group build (1 wave) ----------------
__global__ __launch_bounds__(64) void finalize_scene_kernel(
    const float* __restrict__ scene_b, float* __restrict__ logits,
    int* __restrict__ idx_ws, int* __restrict__ grp_scene, int* __restrict__ grp_samp,
    float* __restrict__ out)
{
    const int b = threadIdx.x;
    const float bias = scene_b[0];
    float lg[SS];
    float m = -1e30f; int am = 0;
    #pragma unroll
    for (int s = 0; s < SS; ++s) {
        lg[s] = logits[b * SS + s] + bias;
        if (lg[s] > m) { m = lg[s]; am = s; }   // first-max tie-break
    }
    float sum = 0.f;
    #pragma unroll
    for (int s = 0; s < SS; ++s) sum += expf(lg[s] - m);
    const float lse = m + logf(sum);
    #pragma unroll
    for (int s = 0; s < SS; ++s) out[BB * 7 + b * SS + s] = lg[s] - lse;
    idx_ws[b] = am;

    // ---- build groups of <=GG samples per scene ----
    __shared__ int sh_cnt[SS];
    __shared__ int sh_base[SS];
    __shared__ int sh_scene[NG];
    __shared__ int sh_samp[NG][GG];

    for (int i = b; i < NG; i += 64) sh_scene[i] = -1;
    for (int i = b; i < NG * GG; i += 64) ((int*)sh_samp)[i] = -1;

    int rank = 0;
    for (int s = 0; s < SS; ++s) {
        unsigned long long mk = __ballot(am == s);
        if (am == s) rank = __popcll(mk & ((1ull << b) - 1ull));
        if (b == s) sh_cnt[s] = (int)__popcll(mk);
    }
    __syncthreads();
    if (b == 0) {
        int acc = 0;
        for (int s = 0; s < SS; ++s) {
            sh_base[s] = acc;
            acc += (sh_cnt[s] + GG - 1) / GG;
        }
    }
    __syncthreads();
    {
        const int g = sh_base[am] + rank / GG;
        const int slot = rank % GG;
        sh_samp[g][slot] = b;
        if (slot == 0) sh_scene[g] = am;
    }
    __syncthreads();
    for (int i = b; i < NG; i += 64) grp_scene[i] = sh_scene[i];
    for (int i = b; i < NG * GG; i += 64) grp_samp[i] = ((int*)sh_samp)[i];
}

// ---------------- Kernel B: layer-1 matvec, uniform one-pass groups ----------------
// grid (DSPL, NG, 2). Each block: one group's DS-row x 1024-col slice of W1[scene].
// Per thread: 4 consecutive H-cols, GG accumulators, 8-row W register buffer.
template<int DSPL>
__global__ __launch_bounds__(256) void layer1_kernel(
    const float* __restrict__ descs_t, const float* __restrict__ descs_rot,
    const float* __restrict__ Wt1, const float* __restrict__ Wr1,
    const int* __restrict__ grp_scene, const int* __restrict__ grp_samp,
    float* __restrict__ part)
{
    constexpr int DS = DD / DSPL;      // rows per block
    const int dsp  = blockIdx.x;
    const int g    = blockIdx.y;
    const int head = blockIdx.z;
    const int tid  = threadIdx.x;

    const int s = grp_scene[g];
    if (s < 0) return;

    __shared__ int   sh_b[GG];
    __shared__ float sh_g[DS][GG];     // transposed: row d holds all GG samples
    if (tid < GG) sh_b[tid] = grp_samp[g * GG + tid];
    __syncthreads();

    const float* descs = head ? descs_rot : descs_t;
    // stage g slices, transposed into sh_g[d][p]
    for (int t = tid; t < GG * (DS / 4); t += 256) {
        const int p = t / (DS / 4);
        const int c = t % (DS / 4);
        const int b = sh_b[p];
        float4 v = make_float4(0.f, 0.f, 0.f, 0.f);
        if (b >= 0)
            v = ((const float4*)(descs + ((size_t)b * SS + s) * DD + dsp * DS))[c];
        sh_g[c * 4 + 0][p] = v.x;
        sh_g[c * 4 + 1][p] = v.y;
        sh_g[c * 4 + 2][p] = v.z;
        sh_g[c * 4 + 3][p] = v.w;
    }
    __syncthreads();

    const float* W = (head ? Wr1 : Wt1)
                   + (size_t)s * DD * HH + (size_t)dsp * DS * HH + tid * 4;

    float4 acc[GG];
    #pragma unroll
    for (int p = 0; p < GG; ++p) acc[p] = make_float4(0.f, 0.f, 0.f, 0.f);

    for (int d0 = 0; d0 < DS; d0 += 8) {
        float4 w[8];
        #pragma unroll
        for (int r = 0; r < 8; ++r)
            w[r] = *(const float4*)(W + (size_t)(d0 + r) * HH);
        #pragma unroll
        for (int r = 0; r < 8; ++r) {
            const float4 ga = *(const float4*)&sh_g[d0 + r][0];  // broadcast
            const float4 gb = *(const float4*)&sh_g[d0 + r][4];
            acc[0].x += ga.x*w[r].x; acc[0].y += ga.x*w[r].y; acc[0].z += ga.x*w[r].z; acc[0].w += ga.x*w[r].w;
            acc[1].x += ga.y*w[r].x; acc[1].y += ga.y*w[r].y; acc[1].z += ga.y*w[r].z; acc[1].w += ga.y*w[r].w;
            acc[2].x += ga.z*w[r].x; acc[2].y += ga.z*w[r].y; acc[2].z += ga.z*w[r].z; acc[2].w += ga.z*w[r].w;
            acc[3].x += ga.w*w[r].x; acc[3].y += ga.w*w[r].y; acc[3].z += ga.w*w[r].z; acc[3].w += ga.w*w[r].w;
            acc[4].x += gb.x*w[r].x; acc[4].y += gb.x*w[r].y; acc[4].z += gb.x*w[r].z; acc[4].w += gb.x*w[r].w;
            acc[5].x += gb.y*w[r].x; acc[5].y += gb.y*w[r].y; acc[5].z += gb.y*w[r].z; acc[5].w += gb.y*w[r].w;
            acc[6].x += gb.z*w[r].x; acc[6].y += gb.z*w[r].y; acc[6].z += gb.z*w[r].z; acc[6].w += gb.z*w[r].w;
            acc[7].x += gb.w*w[r].x; acc[7].y += gb.w*w[r].y; acc[7].z += gb.w*w[r].z; acc[7].w += gb.w*w[r].w;
        }
    }

    #pragma unroll
    for (int p = 0; p < GG; ++p) {
        const int b = sh_b[p];
        if (b >= 0) {
            float* dst = part + (((size_t)(head * BB + b) * DSPL + dsp) * HH) + tid * 4;
            *(float4*)dst = acc[p];
        }
    }
}

// ---------------- Kernel C: bias + GELU + layer-2 + pose output ----------------
template<int DSPL>
__global__ __launch_bounds__(256) void head_out_kernel(
    const float* __restrict__ bt1, const float* __restrict__ Wt2, const float* __restrict__ bt2,
    const float* __restrict__ br1, const float* __restrict__ Wr2, const float* __restrict__ br2,
    const int* __restrict__ idx_ws, const float* __restrict__ part,
    float* __restrict__ out)
{
    const int b   = blockIdx.x;
    const int tid = threadIdx.x;
    const int s   = idx_ws[b];

    __shared__ float sh_h[2][HH];
    __shared__ float sh_red[7][4];

    #pragma unroll
    for (int head = 0; head < 2; ++head) {
        const float* b1 = (head ? br1 : bt1) + (size_t)s * HH;
        const float* p0 = part + ((size_t)(head * BB + b) * DSPL) * HH;
        const int j = tid * 4;
        float4 a = *(const float4*)(p0 + j);
        #pragma unroll
        for (int dsp = 1; dsp < DSPL; ++dsp) {
            float4 q = *(const float4*)(p0 + (size_t)dsp * HH + j);
            a.x += q.x; a.y += q.y; a.z += q.z; a.w += q.w;
        }
        float4 bb = *(const float4*)(b1 + j);
        sh_h[head][j + 0] = gelu_exact(a.x + bb.x);
        sh_h[head][j + 1] = gelu_exact(a.y + bb.y);
        sh_h[head][j + 2] = gelu_exact(a.z + bb.z);
        sh_h[head][j + 3] = gelu_exact(a.w + bb.w);
    }
    __syncthreads();

    const float* wt2 = Wt2 + (size_t)s * HH * 3;
    const float* wr2 = Wr2 + (size_t)s * HH * 4;
    float pa[7] = {0.f, 0.f, 0.f, 0.f, 0.f, 0.f, 0.f};
    for (int j = tid; j < HH; j += 256) {
        float ht = sh_h[0][j];
        float hr = sh_h[1][j];
        pa[0] += ht * wt2[j * 3 + 0];
        pa[1] += ht * wt2[j * 3 + 1];
        pa[2] += ht * wt2[j * 3 + 2];
        pa[3] += hr * wr2[j * 4 + 0];
        pa[4] += hr * wr2[j * 4 + 1];
        pa[5] += hr * wr2[j * 4 + 2];
        pa[6] += hr * wr2[j * 4 + 3];
    }
    const int lane = tid & 63, wave = tid >> 6;
    #pragma unroll
    for (int o = 0; o < 7; ++o) {
        float v = pa[o];
        #pragma unroll
        for (int off = 32; off >= 1; off >>= 1) v += __shfl_xor(v, off, 64);
        if (lane == 0) sh_red[o][wave] = v;
    }
    __syncthreads();
    if (tid < 7) {
        float v = sh_red[tid][0] + sh_red[tid][1] + sh_red[tid][2] + sh_red[tid][3];
        float bias = (tid < 3) ? bt2[(size_t)s * 3 + tid] : br2[(size_t)s * 4 + (tid - 3)];
        out[b * 7 + tid] = v + bias;
    }
}

template<int DSPL>
static void launch_pipeline(const float* descs_t, const float* descs_rot,
                            const float* Wt1, const float* Wr1,
                            const float* bt1, const float* Wt2, const float* bt2,
                            const float* br1, const float* Wr2, const float* br2,
                            int* idx_ws, int* grp_scene, int* grp_samp, float* part,
                            float* out, hipStream_t stream) {
    layer1_kernel<DSPL><<<dim3(DSPL, NG, 2), dim3(256), 0, stream>>>(
        descs_t, descs_rot, Wt1, Wr1, grp_scene, grp_samp, part);
    head_out_kernel<DSPL><<<dim3(BB), dim3(256), 0, stream>>>(
        bt1, Wt2, bt2, br1, Wr2, br2, idx_ws, part, out);
}

extern "C" void kernel_launch(void* const* d_in, const int* in_sizes, int n_in,
                              void* d_out, int out_size, void* d_ws, size_t ws_size,
                              hipStream_t stream) {
    const float* descs_t   = (const float*)d_in[0];
    const float* descs_rot = (const float*)d_in[1];
    const float* scene_w   = (const float*)d_in[2];
    const float* scene_b   = (const float*)d_in[3];
    const float* Wt1 = (const float*)d_in[4];
    const float* bt1 = (const float*)d_in[5];
    const float* Wt2 = (const float*)d_in[6];
    const float* bt2 = (const float*)d_in[7];
    const float* Wr1 = (const float*)d_in[8];
    const float* br1 = (const float*)d_in[9];
    const float* Wr2 = (const float*)d_in[10];
    const float* br2 = (const float*)d_in[11];
    float* out = (float*)d_out;

    int*   idx_ws    = (int*)d_ws;
    float* logits    = (float*)((char*)d_ws + WS_LOGITS);
    int*   grp_scene = (int*)((char*)d_ws + WS_GSCENE);
    int*   grp_samp  = (int*)((char*)d_ws + WS_GSAMP);
    float* part      = (float*)((char*)d_ws + WS_PART);

    logits_kernel<<<dim3(SS, BB), dim3(256), 0, stream>>>(
        descs_t, descs_rot, scene_w, logits);
    finalize_scene_kernel<<<dim3(1), dim3(64), 0, stream>>>(
        scene_b, logits, idx_ws, grp_scene, grp_samp, out);

    const size_t need16 = (size_t)WS_PART + (size_t)2 * BB * 16 * HH * sizeof(float);
    const size_t need8  = (size_t)WS_PART + (size_t)2 * BB * 8  * HH * sizeof(float);
    if (ws_size >= need16) {
        launch_pipeline<16>(descs_t, descs_rot, Wt1, Wr1, bt1, Wt2, bt2, br1, Wr2, br2,
                            idx_ws, grp_scene, grp_samp, part, out, stream);
    } else if (ws_size >= need8) {
        launch_pipeline<8>(descs_t, descs_rot, Wt1, Wr1, bt1, Wt2, bt2, br1, Wr2, br2,
                            idx_ws, grp_scene, grp_samp, part, out, stream);
    } else {
        launch_pipeline<4>(descs_t, descs_rot, Wt1, Wr1, bt1, Wt2, bt2, br1, Wr2, br2,
                            idx_ws, grp_scene, grp_samp, part, out, stream);
    }
}